// Round 3
// baseline (242.366 us; speedup 1.0000x reference)
//
#include <hip/hip_runtime.h>
#include <hip/hip_bf16.h>

#define HEADS 4
#define DH    128
#define CIN   256
#define NPIX  16384
#define NB    4
#define HID   512

typedef __attribute__((ext_vector_type(8))) short bf16x8;
typedef __attribute__((ext_vector_type(4))) float f32x4;

__device__ __forceinline__ float bf2f(unsigned short u) {
    return __uint_as_float(((unsigned)u) << 16);
}
__device__ __forceinline__ unsigned short f2bfu(float f) {
    union { __hip_bfloat16 h; unsigned short u; } cv;
    cv.h = __float2bfloat16(f);
    return cv.u;
}

// ---- async global->LDS, 16B per lane -------------------------------------
typedef const __attribute__((address_space(1))) unsigned char* gas_t;
typedef __attribute__((address_space(3))) unsigned char* las_t;
__device__ __forceinline__ void glds16(const void* g, void* s) {
    __builtin_amdgcn_global_load_lds((gas_t)g, (las_t)s, 16, 0, 0);
}

// LDS tile: 128 rows x 64 bf16 (128B row). Logical 16B slot s of row r lives
// at physical slot s ^ (r&7).  ds_read side:
__device__ __forceinline__ int swz(int row, int usoff) {
    return row * 64 + (usoff ^ ((row & 7) << 3));
}

// Stage one 128x64 bf16 tile via global_load_lds. LDS dest is linear
// (wave-uniform base + lane*16); the swizzle is applied to the per-lane
// GLOBAL source address (m173 pattern). ldk = row stride in ushorts.
__device__ __forceinline__ void stage_glds(const unsigned short* __restrict__ g,
                                           size_t ldk, unsigned short* lbuf, int t)
{
    const int w  = t >> 6;
    const int l  = t & 63;
    const int r0 = l >> 3;   // 0..7
    const int sl = l & 7;    // 16B slot
#pragma unroll
    for (int i = 0; i < 4; ++i) {
        const int row = w * 32 + i * 8 + r0;
        const unsigned short* src = g + (size_t)row * ldk + ((sl ^ (row & 7)) << 3);
        unsigned short* dst = lbuf + (size_t)(w * 32 + i * 8) * 64;   // wave-uniform
        glds16(src, dst);
    }
}

// 4 waves, wave (wr,wc) owns a 64x64 quadrant = 4x4 fragments of 16x16.
__device__ __forceinline__ void mfma_tile(const unsigned short* sA,
                                          const unsigned short* sB,
                                          f32x4 (&acc)[4][4], int t)
{
    const int lane = t & 63, wid = t >> 6;
    const int wr = (wid >> 1) * 64, wc = (wid & 1) * 64;
    const int lrow = lane & 15, lk = (lane >> 4) * 8;
#pragma unroll
    for (int ks = 0; ks < 2; ++ks) {
        bf16x8 a[4], b[4];
#pragma unroll
        for (int f = 0; f < 4; ++f) {
            a[f] = *reinterpret_cast<const bf16x8*>(&sA[swz(wr + f * 16 + lrow, ks * 32 + lk)]);
            b[f] = *reinterpret_cast<const bf16x8*>(&sB[swz(wc + f * 16 + lrow, ks * 32 + lk)]);
        }
#pragma unroll
        for (int fi = 0; fi < 4; ++fi)
#pragma unroll
            for (int fj = 0; fj < 4; ++fj)
                acc[fi][fj] = __builtin_amdgcn_mfma_f32_16x16x32_bf16(
                    a[fi], b[fj], acc[fi][fj], 0, 0, 0);
    }
}

// ---------------------------------------------------------------------------
// K0a: x[b][c][n] fp32 -> xt[b][n][c] bf16 (vectorized transpose)
// grid (256, 4, 4), block 256
// ---------------------------------------------------------------------------
__global__ __launch_bounds__(256) void xt_convert(const float* __restrict__ x,
                                                  unsigned short* __restrict__ xt)
{
    __shared__ float tile[64][65];
    const int b = blockIdx.z, c0 = blockIdx.y * 64, n0 = blockIdx.x * 64;
    const int t = threadIdx.x;
    const float* xb = x + ((size_t)b * CIN + c0) * NPIX + n0;
#pragma unroll
    for (int p = 0; p < 4; ++p) {
        const int c = p * 16 + (t >> 4);
        const int n = (t & 15) * 4;
        float4 v = *reinterpret_cast<const float4*>(xb + (size_t)c * NPIX + n);
        tile[c][n + 0] = v.x; tile[c][n + 1] = v.y;
        tile[c][n + 2] = v.z; tile[c][n + 3] = v.w;
    }
    __syncthreads();
    unsigned short* dst = xt + ((size_t)b * NPIX + n0) * CIN + c0;
#pragma unroll
    for (int p = 0; p < 2; ++p) {
        const int n  = p * 32 + (t >> 3);
        const int c8 = (t & 7) * 8;
        unsigned short u8[8];
#pragma unroll
        for (int j = 0; j < 8; ++j) u8[j] = f2bfu(tile[c8 + j][n]);
        *reinterpret_cast<uint4*>(dst + (size_t)n * CIN + c8) = *reinterpret_cast<const uint4*>(u8);
    }
}

// K0b: w_qkv fp32 -> bf16
__global__ __launch_bounds__(256) void wconv(const float* __restrict__ w,
                                             unsigned short* __restrict__ wbf)
{
    const int i = blockIdx.x * 256 + threadIdx.x;
    wbf[i] = f2bfu(w[i]);
}

// ---------------------------------------------------------------------------
// K1: kv GEMM + fused softmax.  logit[m,n] = sum_c W[512+m,c]*xt[n,c].
//     m<512: store bf16(exp(logit)) to pbuf, atomicAdd row sums into S.
//     m>=512: store bf16(logit) to vbuf.
// 2-phase glds pipeline, LDS-bounce coalesced epilogue.
// grid (128, 8, 4), block 256
// ---------------------------------------------------------------------------
__global__ __launch_bounds__(256) void kv_gemm_mfma(const unsigned short* __restrict__ xt,
                                                    const unsigned short* __restrict__ wbf,
                                                    unsigned short* __restrict__ pbuf,
                                                    unsigned short* __restrict__ vbuf,
                                                    float* __restrict__ S)
{
    __shared__ unsigned short lds[2][2][128 * 64];   // 64 KB
    const int t  = threadIdx.x;
    const int n0 = blockIdx.x * 128;
    const int m0 = blockIdx.y * 128;
    const int b  = blockIdx.z;
    const unsigned short* gA = wbf + (size_t)(512 + m0) * CIN;
    const unsigned short* gB = xt + ((size_t)b * NPIX + n0) * CIN;

    f32x4 acc[4][4] = {};
    stage_glds(gA, CIN, lds[0][0], t);
    stage_glds(gB, CIN, lds[0][1], t);
    __syncthreads();
#pragma unroll
    for (int kt = 0; kt < 4; ++kt) {
        const int cur = kt & 1;
        if (kt < 3) {
            stage_glds(gA + (kt + 1) * 64, CIN, lds[cur ^ 1][0], t);
            stage_glds(gB + (kt + 1) * 64, CIN, lds[cur ^ 1][1], t);
        }
        mfma_tile(lds[cur][0], lds[cur][1], acc, t);
        __syncthreads();
    }

    const int lane = t & 63, wid = t >> 6;
    const int wr = (wid >> 1) * 64, wc = (wid & 1) * 64;
    const int col = lane & 15, r0q = (lane >> 4) * 4;
    const bool isK = (m0 < 512);

    // bounce quadrant through LDS (row stride 72 ushorts = 144B, 16B aligned)
    unsigned short* reg = &lds[0][0][0] + (size_t)wid * (64 * 72);
#pragma unroll
    for (int fi = 0; fi < 4; ++fi)
#pragma unroll
        for (int r = 0; r < 4; ++r) {
            float rs = 0.f;
#pragma unroll
            for (int fj = 0; fj < 4; ++fj) {
                float v = acc[fi][fj][r];
                if (isK) { v = __expf(v); rs += v; }
                reg[(fi * 16 + r0q + r) * 72 + fj * 16 + col] = f2bfu(v);
            }
            if (isK) {
                rs += __shfl_xor(rs, 1); rs += __shfl_xor(rs, 2);
                rs += __shfl_xor(rs, 4); rs += __shfl_xor(rs, 8);
                if (col == 0)
                    atomicAdd(&S[(size_t)b * 512 + m0 + wr + fi * 16 + r0q + r], rs);
            }
        }
    __syncthreads();

    unsigned short* base = isK ? pbuf : vbuf;
    const int mb = isK ? m0 : m0 - 512;
#pragma unroll
    for (int p = 0; p < 8; ++p) {
        const int q  = p * 8 + (lane >> 3);
        const int sl = lane & 7;
        uint4 u = *reinterpret_cast<const uint4*>(&reg[q * 72 + sl * 8]);
        *reinterpret_cast<uint4*>(
            &base[((size_t)b * 512 + mb + wr + q) * NPIX + n0 + wc + sl * 8]) = u;
    }
}

// ---------------------------------------------------------------------------
// K3: ctx partials.  partial[ksp,bh,d,e] = sum_{n in split} p[d,n]*v[e,n]
// grid (32, 16), block 256.  Pure glds staging (exp already applied).
// ---------------------------------------------------------------------------
__global__ __launch_bounds__(256) void ctx_mfma(const unsigned short* __restrict__ pbuf,
                                                const unsigned short* __restrict__ vbuf,
                                                float* __restrict__ partial)
{
    __shared__ unsigned short lds[2][2][128 * 64];
    const int t   = threadIdx.x;
    const int ksp = blockIdx.x;
    const int bh  = blockIdx.y;
    const unsigned short* gA = pbuf + (size_t)bh * DH * NPIX + ksp * 512;
    const unsigned short* gB = vbuf + (size_t)bh * DH * NPIX + ksp * 512;

    f32x4 acc[4][4] = {};
    stage_glds(gA, NPIX, lds[0][0], t);
    stage_glds(gB, NPIX, lds[0][1], t);
    __syncthreads();
#pragma unroll
    for (int kt = 0; kt < 8; ++kt) {
        const int cur = kt & 1;
        if (kt < 7) {
            stage_glds(gA + (kt + 1) * 64, NPIX, lds[cur ^ 1][0], t);
            stage_glds(gB + (kt + 1) * 64, NPIX, lds[cur ^ 1][1], t);
        }
        mfma_tile(lds[cur][0], lds[cur][1], acc, t);
        __syncthreads();
    }

    float* dst = partial + ((size_t)ksp * 16 + bh) * (DH * DH);
    const int lane = t & 63, wid = t >> 6;
    const int wr = (wid >> 1) * 64, wc = (wid & 1) * 64;
    const int col = lane & 15, r0q = (lane >> 4) * 4;
#pragma unroll
    for (int fi = 0; fi < 4; ++fi)
#pragma unroll
        for (int fj = 0; fj < 4; ++fj)
#pragma unroll
            for (int r = 0; r < 4; ++r)
                dst[(wr + fi * 16 + r0q + r) * DH + wc + fj * 16 + col] = acc[fi][fj][r];
}

// K4: ctx_s[bh,d,e] = (1/S[bh*128+d]) * sum_ksp partial[ksp,bh,d,e]
__global__ __launch_bounds__(256) void ctx_reduce(const float* __restrict__ partial,
                                                  const float* __restrict__ S,
                                                  float* __restrict__ ctx_s)
{
    const int idx = blockIdx.x * 256 + threadIdx.x;   // 16 * 16384
    const int bh = idx >> 14, de = idx & 16383;
    const int d  = de >> 7;
    float s = 0.f;
#pragma unroll
    for (int k = 0; k < 32; ++k)
        s += partial[((size_t)k * 16 + bh) * 16384 + de];
    ctx_s[idx] = s * (1.0f / S[bh * 128 + d]);
}

// K5: Abar[b, h*128+e, c] = sum_d ctx_s[bh,d,e] * w_q[h*128+d, c]
__global__ __launch_bounds__(256) void abar_kernel(const float* __restrict__ ctx_s,
                                                   const float* __restrict__ w_qkv,
                                                   float* __restrict__ Abar)
{
    const int m = blockIdx.x, b = blockIdx.y;
    const int h = m >> 7, e = m & 127;
    const int c = threadIdx.x;
    const float* cx = ctx_s + (size_t)(b * HEADS + h) * (DH * DH);
    float s = 0.f;
    for (int d = 0; d < DH; ++d)
        s += cx[d * DH + e] * w_qkv[(size_t)(h * DH + d) * CIN + c];
    Abar[((size_t)b * HID + m) * CIN + c] = s;
}

// K6: fbf[b,o,c] = bf16( sum_m w_out[o,m] * Abar[b,m,c] )
__global__ __launch_bounds__(256) void f_kernel(const float* __restrict__ Abar,
                                                const float* __restrict__ w_out,
                                                unsigned short* __restrict__ fbf)
{
    const int o = blockIdx.x, b = blockIdx.y;
    const int c = threadIdx.x;
    const float* ab = Abar + (size_t)b * HID * CIN + c;
    const float* wo = w_out + (size_t)o * HID;
    float s = 0.f;
    for (int m = 0; m < HID; ++m) s += wo[m] * ab[(size_t)m * CIN];
    fbf[((size_t)b * CIN + o) * CIN + c] = f2bfu(s);
}

// ---------------------------------------------------------------------------
// K7: out GEMM. out[b,o,n] = sum_c fbf[o,c]*xt[n,c] + b_out[o]
// grid (128, 2, 4), block 256
// ---------------------------------------------------------------------------
__global__ __launch_bounds__(256) void out_gemm_mfma(const unsigned short* __restrict__ xt,
                                                     const unsigned short* __restrict__ fbf,
                                                     const float* __restrict__ b_out,
                                                     float* __restrict__ out)
{
    __shared__ unsigned short lds[2][2][128 * 64];
    const int t  = threadIdx.x;
    const int n0 = blockIdx.x * 128;
    const int m0 = blockIdx.y * 128;
    const int b  = blockIdx.z;
    const unsigned short* gA = fbf + ((size_t)b * CIN + m0) * CIN;
    const unsigned short* gB = xt + ((size_t)b * NPIX + n0) * CIN;

    f32x4 acc[4][4] = {};
    stage_glds(gA, CIN, lds[0][0], t);
    stage_glds(gB, CIN, lds[0][1], t);
    __syncthreads();
#pragma unroll
    for (int kt = 0; kt < 4; ++kt) {
        const int cur = kt & 1;
        if (kt < 3) {
            stage_glds(gA + (kt + 1) * 64, CIN, lds[cur ^ 1][0], t);
            stage_glds(gB + (kt + 1) * 64, CIN, lds[cur ^ 1][1], t);
        }
        mfma_tile(lds[cur][0], lds[cur][1], acc, t);
        __syncthreads();
    }

    const int lane = t & 63, wid = t >> 6;
    const int wr = (wid >> 1) * 64, wc = (wid & 1) * 64;
    const int col = lane & 15, r0q = (lane >> 4) * 4;
#pragma unroll
    for (int fi = 0; fi < 4; ++fi)
#pragma unroll
        for (int r = 0; r < 4; ++r) {
            const int o = m0 + wr + fi * 16 + r0q + r;
            const float bias = b_out[o];
#pragma unroll
            for (int fj = 0; fj < 4; ++fj)
                out[((size_t)b * CIN + o) * NPIX + n0 + wc + fj * 16 + col] =
                    acc[fi][fj][r] + bias;
        }
}

// ---------------------------------------------------------------------------
extern "C" void kernel_launch(void* const* d_in, const int* in_sizes, int n_in,
                              void* d_out, int out_size, void* d_ws, size_t ws_size,
                              hipStream_t stream)
{
    const float* x     = (const float*)d_in[0];
    const float* w_qkv = (const float*)d_in[1];
    const float* w_out = (const float*)d_in[2];
    const float* b_out = (const float*)d_in[3];
    float* out = (float*)d_out;

    char* ws = (char*)d_ws;
    unsigned short* xt   = (unsigned short*)ws;                      // 32 MB
    unsigned short* pbuf = (unsigned short*)(ws + (32ull  << 20));   // 64 MB
    unsigned short* vbuf = (unsigned short*)(ws + (96ull  << 20));   // 64 MB
    unsigned short* wbf  = (unsigned short*)(ws + (160ull << 20));   // 768 KB
    float*          S    = (float*)(ws + (161ull << 20));            // 8 KB
    // pbuf/vbuf dead after ctx_mfma -> reuse:
    float*          ctx_s = (float*)(ws + (32ull << 20));            // 1 MB
    float*          Abar  = (float*)(ws + (33ull << 20));            // 2 MB
    unsigned short* fbf   = (unsigned short*)(ws + (35ull << 20));   // 512 KB
    float* partial = (float*)d_out;                                  // 32 MB (dead until out_gemm)

    hipMemsetAsync(S, 0, 2048 * sizeof(float), stream);
    xt_convert<<<dim3(NPIX / 64, CIN / 64, NB), 256, 0, stream>>>(x, xt);
    wconv<<<(1536 * 256) / 256, 256, 0, stream>>>(w_qkv, wbf);
    kv_gemm_mfma<<<dim3(NPIX / 128, 1024 / 128, NB), 256, 0, stream>>>(xt, wbf, pbuf, vbuf, S);
    ctx_mfma<<<dim3(32, 16), 256, 0, stream>>>(pbuf, vbuf, partial);
    ctx_reduce<<<(16 * 16384) / 256, 256, 0, stream>>>(partial, S, ctx_s);
    abar_kernel<<<dim3(512, NB), 256, 0, stream>>>(ctx_s, w_qkv, Abar);
    f_kernel<<<dim3(256, NB), 256, 0, stream>>>(Abar, w_out, fbf);
    out_gemm_mfma<<<dim3(NPIX / 128, CIN / 128, NB), 256, 0, stream>>>(xt, fbf, b_out, out);
}

// Round 4
// 186.324 us; speedup vs baseline: 1.3008x; 1.3008x over previous
//
#include <hip/hip_runtime.h>
#include <hip/hip_bf16.h>

#define HEADS 4
#define DH    128
#define CIN   256
#define NPIX  16384
#define NB    4
#define HID   512

typedef __attribute__((ext_vector_type(8))) short bf16x8;
typedef __attribute__((ext_vector_type(4))) float f32x4;

__device__ __forceinline__ float bf2f(unsigned short u) {
    return __uint_as_float(((unsigned)u) << 16);
}
__device__ __forceinline__ unsigned short f2bfu(float f) {
    union { __hip_bfloat16 h; unsigned short u; } cv;
    cv.h = __float2bfloat16(f);
    return cv.u;
}

// ---- async global->LDS, 16B per lane -------------------------------------
typedef const __attribute__((address_space(1))) unsigned char* gas_t;
typedef __attribute__((address_space(3))) unsigned char* las_t;
__device__ __forceinline__ void glds16(const void* g, void* s) {
    __builtin_amdgcn_global_load_lds((gas_t)g, (las_t)s, 16, 0, 0);
}

// 64-ushort-wide LDS rows: logical 16B slot s of row r at phys slot s^(r&7)
__device__ __forceinline__ int swz(int row, int usoff) {
    return row * 64 + (usoff ^ ((row & 7) << 3));
}
// 128-ushort-wide rows (P buffer)
__device__ __forceinline__ int swzP(int row, int usoff) {
    return row * 128 + (usoff ^ ((row & 7) << 3));
}

// stage NR rows x 64 cols bf16 tile, 512 threads, glds + pre-swizzled source
template<int NR>
__device__ __forceinline__ void stage512(const unsigned short* __restrict__ g,
                                         size_t ldk, unsigned short* lbuf, int t)
{
    const int w = t >> 6, l = t & 63;
    const int sl = l & 7;
#pragma unroll
    for (int i = 0; i < NR / 64; ++i) {
        const int row = i * 64 + w * 8 + (l >> 3);
        glds16(g + (size_t)row * ldk + ((sl ^ (row & 7)) << 3),
               lbuf + (size_t)(i * 64 + w * 8) * 64);
    }
}

// stage 128x64 with 256 threads (for out_gemm)
__device__ __forceinline__ void stage256(const unsigned short* __restrict__ g,
                                         size_t ldk, unsigned short* lbuf, int t)
{
    const int w = t >> 6, l = t & 63;
    const int sl = l & 7;
#pragma unroll
    for (int i = 0; i < 4; ++i) {
        const int row = w * 32 + i * 8 + (l >> 3);
        glds16(g + (size_t)row * ldk + ((sl ^ (row & 7)) << 3),
               lbuf + (size_t)(w * 32 + i * 8) * 64);
    }
}

// ---------------------------------------------------------------------------
// K0a: x[b][c][n] fp32 -> xt[b][n][c] bf16 AND xbf[b][c][n] bf16
// grid (256, 4, 4), block 256
// ---------------------------------------------------------------------------
__global__ __launch_bounds__(256) void xt_convert(const float* __restrict__ x,
                                                  unsigned short* __restrict__ xt,
                                                  unsigned short* __restrict__ xbf)
{
    __shared__ float tile[64][65];
    const int b = blockIdx.z, c0 = blockIdx.y * 64, n0 = blockIdx.x * 64;
    const int t = threadIdx.x;
    const float* xb = x + ((size_t)b * CIN + c0) * NPIX + n0;
#pragma unroll
    for (int p = 0; p < 4; ++p) {
        const int c = p * 16 + (t >> 4);
        const int n = (t & 15) * 4;
        float4 v = *reinterpret_cast<const float4*>(xb + (size_t)c * NPIX + n);
        tile[c][n + 0] = v.x; tile[c][n + 1] = v.y;
        tile[c][n + 2] = v.z; tile[c][n + 3] = v.w;
    }
    __syncthreads();
    // xt[n][c]
    unsigned short* dst = xt + ((size_t)b * NPIX + n0) * CIN + c0;
#pragma unroll
    for (int p = 0; p < 2; ++p) {
        const int n  = p * 32 + (t >> 3);
        const int c8 = (t & 7) * 8;
        unsigned short u8[8];
#pragma unroll
        for (int j = 0; j < 8; ++j) u8[j] = f2bfu(tile[c8 + j][n]);
        *reinterpret_cast<uint4*>(dst + (size_t)n * CIN + c8) = *reinterpret_cast<const uint4*>(u8);
    }
    // xbf[c][n]
    const int c_loc = t >> 2;
    const int n16   = (t & 3) * 16;
    unsigned short u16[16];
#pragma unroll
    for (int j = 0; j < 16; ++j) u16[j] = f2bfu(tile[c_loc][n16 + j]);
    unsigned short* db = xbf + ((size_t)b * CIN + c0 + c_loc) * NPIX + n0 + n16;
    *reinterpret_cast<uint4*>(db)     = *reinterpret_cast<const uint4*>(u16);
    *reinterpret_cast<uint4*>(db + 8) = *reinterpret_cast<const uint4*>(u16 + 8);
}

// K0b: w_qkv fp32 -> bf16
__global__ __launch_bounds__(256) void wconv(const float* __restrict__ w,
                                             unsigned short* __restrict__ wbf)
{
    const int i = blockIdx.x * 256 + threadIdx.x;
    wbf[i] = f2bfu(w[i]);
}

// ---------------------------------------------------------------------------
// K1 (fused): per (n-split, h, b):
//   GEMM1: logit[d,n] = sum_c Wk[d,c] xt[n,c]   (128 x 128 tile, K=256)
//   P = exp(logit) -> LDS (bf16, swizzled); S rowsums accumulated
//   GEMM2: G[d,c] += sum_n P[d,n] xbf[c,n]      (accumulated over n-split)
// grid (16, 4, 4), block 512 (8 waves), 128 KB LDS
// ---------------------------------------------------------------------------
__global__ __launch_bounds__(512, 2) void kg_fused(const unsigned short* __restrict__ xt,
                                                   const unsigned short* __restrict__ xbf,
                                                   const unsigned short* __restrict__ wbf,
                                                   float* __restrict__ Gp,
                                                   float* __restrict__ S)
{
    __shared__ unsigned short sA1[2][128 * 64];   // 32 KB  Wk tiles (dbuf)
    __shared__ unsigned short sB1[2][128 * 64];   // 32 KB  xt tiles (dbuf)
    __shared__ unsigned short sP[128 * 128];      // 32 KB  exp(logits)
    __shared__ unsigned short sB2[256 * 64];      // 32 KB  xbf chunk

    const int t  = threadIdx.x;
    const int ns = blockIdx.x;            // n-split: 1024 pixels
    const int h  = blockIdx.y;
    const int b  = blockIdx.z;
    const int bh = b * 4 + h;
    const int lane = t & 63, wid = t >> 6;
    const int wm = wid >> 1, wn = wid & 1;      // GEMM1: 4x2 waves, 32d x 64n each
    const int wd = wid >> 2, wcq = wid & 3;     // GEMM2: 2x4 waves, 64d x 64c each
    const int lrow = lane & 15, lk = (lane >> 4) * 8;
    const int cl = lane & 15, r0q = (lane >> 4) * 4;

    const unsigned short* gW  = wbf + (size_t)(512 + h * 128) * CIN;
    const unsigned short* gXT = xt + ((size_t)b * NPIX + ns * 1024) * CIN;
    const unsigned short* gXB = xbf + (size_t)b * CIN * NPIX + ns * 1024;

    f32x4 accG[4][4] = {};
    float Sacc[8] = {};

    for (int nt = 0; nt < 8; ++nt) {
        // issue GEMM2-B chunk0 + GEMM1 step0 stages
        stage512<256>(gXB + nt * 128, NPIX, sB2, t);
        stage512<128>(gW, CIN, sA1[0], t);
        stage512<128>(gXT + (size_t)nt * 128 * CIN, CIN, sB1[0], t);
        __syncthreads();

        f32x4 acc1[2][4] = {};
#pragma unroll
        for (int k = 0; k < 4; ++k) {
            const int cur = k & 1;
            if (k < 3) {
                stage512<128>(gW + (k + 1) * 64, CIN, sA1[cur ^ 1], t);
                stage512<128>(gXT + (size_t)nt * 128 * CIN + (k + 1) * 64, CIN, sB1[cur ^ 1], t);
            }
#pragma unroll
            for (int ks = 0; ks < 2; ++ks) {
                bf16x8 a[2], bb[4];
#pragma unroll
                for (int fi = 0; fi < 2; ++fi)
                    a[fi] = *reinterpret_cast<const bf16x8*>(
                        &sA1[cur][swz(wm * 32 + fi * 16 + lrow, ks * 32 + lk)]);
#pragma unroll
                for (int fj = 0; fj < 4; ++fj)
                    bb[fj] = *reinterpret_cast<const bf16x8*>(
                        &sB1[cur][swz(wn * 64 + fj * 16 + lrow, ks * 32 + lk)]);
#pragma unroll
                for (int fi = 0; fi < 2; ++fi)
#pragma unroll
                    for (int fj = 0; fj < 4; ++fj)
                        acc1[fi][fj] = __builtin_amdgcn_mfma_f32_16x16x32_bf16(
                            a[fi], bb[fj], acc1[fi][fj], 0, 0, 0);
            }
            __syncthreads();
        }

        // exp -> P (bf16, swizzled) + rowsum accumulate
#pragma unroll
        for (int fi = 0; fi < 2; ++fi)
#pragma unroll
            for (int r = 0; r < 4; ++r) {
                const int d = wm * 32 + fi * 16 + r0q + r;
                float rs = 0.f;
#pragma unroll
                for (int fj = 0; fj < 4; ++fj) {
                    const float v = __expf(acc1[fi][fj][r]);
                    rs += v;
                    sP[swzP(d, wn * 64 + fj * 16 + cl)] = f2bfu(v);
                }
                Sacc[fi * 4 + r] += rs;
            }
        __syncthreads();

        // GEMM2 over this n-tile (contract n=128 in two 64-chunks)
#pragma unroll
        for (int kn = 0; kn < 2; ++kn) {
            if (kn == 1) {
                stage512<256>(gXB + nt * 128 + 64, NPIX, sB2, t);
                __syncthreads();
            }
#pragma unroll
            for (int ks = 0; ks < 2; ++ks) {
                bf16x8 a[4], bb[4];
#pragma unroll
                for (int fi = 0; fi < 4; ++fi)
                    a[fi] = *reinterpret_cast<const bf16x8*>(
                        &sP[swzP(wd * 64 + fi * 16 + lrow, kn * 64 + ks * 32 + lk)]);
#pragma unroll
                for (int fj = 0; fj < 4; ++fj)
                    bb[fj] = *reinterpret_cast<const bf16x8*>(
                        &sB2[swz(wcq * 64 + fj * 16 + lrow, ks * 32 + lk)]);
#pragma unroll
                for (int fi = 0; fi < 4; ++fi)
#pragma unroll
                    for (int fj = 0; fj < 4; ++fj)
                        accG[fi][fj] = __builtin_amdgcn_mfma_f32_16x16x32_bf16(
                            a[fi], bb[fj], accG[fi][fj], 0, 0, 0);
            }
            __syncthreads();
        }
    }

    // S rowsums: reduce over the 16 col-lanes, atomicAdd once
#pragma unroll
    for (int i = 0; i < 8; ++i) {
        float v = Sacc[i];
        v += __shfl_xor(v, 1); v += __shfl_xor(v, 2);
        v += __shfl_xor(v, 4); v += __shfl_xor(v, 8);
        if (cl == 0) {
            const int d = wm * 32 + (i >> 2) * 16 + r0q + (i & 3);
            atomicAdd(&S[bh * 128 + d], v);
        }
    }

    // G partial write
    float* gp = Gp + (size_t)(ns * 16 + bh) * (128 * 256);
#pragma unroll
    for (int fi = 0; fi < 4; ++fi)
#pragma unroll
        for (int fj = 0; fj < 4; ++fj)
#pragma unroll
            for (int r = 0; r < 4; ++r)
                gp[(size_t)(wd * 64 + fi * 16 + r0q + r) * 256 + wcq * 64 + fj * 16 + cl]
                    = accG[fi][fj][r];
}

// K2: G[bh][d][c] = sum over 16 splits
__global__ __launch_bounds__(256) void g_reduce(const float* __restrict__ Gp,
                                                float* __restrict__ G)
{
    const int idx = blockIdx.x * 256 + threadIdx.x;   // 16 * 32768
    const int bh = idx >> 15, dc = idx & 32767;
    float s = 0.f;
#pragma unroll
    for (int k = 0; k < 16; ++k)
        s += Gp[((size_t)k * 16 + bh) * 32768 + dc];
    G[idx] = s;
}

// K3: ctx_s[bh][d][e] = (1/S[d]) * sum_c G[bh][d][c] * Wv[h*128+e][c]
__global__ __launch_bounds__(128) void ctx_k(const float* __restrict__ G,
                                             const float* __restrict__ w_qkv,
                                             const float* __restrict__ S,
                                             float* __restrict__ ctx_s)
{
    const int d = blockIdx.x, bh = blockIdx.y, h = bh & 3;
    const int e = threadIdx.x;
    const float* g  = G + (size_t)bh * 32768 + d * 256;
    const float* wv = w_qkv + (size_t)(1024 + h * 128 + e) * CIN;
    float s = 0.f;
    for (int c = 0; c < 256; ++c) s += g[c] * wv[c];
    ctx_s[(size_t)bh * 16384 + d * 128 + e] = s / S[bh * 128 + d];
}

// K4: Abar[b, h*128+e, c] = sum_d ctx_s[bh,d,e] * Wq[h*128+d, c]
__global__ __launch_bounds__(256) void abar_kernel(const float* __restrict__ ctx_s,
                                                   const float* __restrict__ w_qkv,
                                                   float* __restrict__ Abar)
{
    const int m = blockIdx.x, b = blockIdx.y;
    const int h = m >> 7, e = m & 127;
    const int c = threadIdx.x;
    const float* cx = ctx_s + (size_t)(b * HEADS + h) * (DH * DH);
    float s = 0.f;
    for (int d = 0; d < DH; ++d)
        s += cx[d * DH + e] * w_qkv[(size_t)(h * DH + d) * CIN + c];
    Abar[((size_t)b * HID + m) * CIN + c] = s;
}

// K5: fbf[b,o,c] = bf16( sum_m w_out[o,m] * Abar[b,m,c] )
__global__ __launch_bounds__(256) void f_kernel(const float* __restrict__ Abar,
                                                const float* __restrict__ w_out,
                                                unsigned short* __restrict__ fbf)
{
    const int o = blockIdx.x, b = blockIdx.y;
    const int c = threadIdx.x;
    const float* ab = Abar + (size_t)b * HID * CIN + c;
    const float* wo = w_out + (size_t)o * HID;
    float s = 0.f;
    for (int m = 0; m < HID; ++m) s += wo[m] * ab[(size_t)m * CIN];
    fbf[((size_t)b * CIN + o) * CIN + c] = f2bfu(s);
}

// ---------------------------------------------------------------------------
// K6: out GEMM. out[b,o,n] = sum_c fbf[o,c]*xt[n,c] + b_out[o]
// grid (128, 2, 4), block 256
// ---------------------------------------------------------------------------
__global__ __launch_bounds__(256) void out_gemm_mfma(const unsigned short* __restrict__ xt,
                                                     const unsigned short* __restrict__ fbf,
                                                     const float* __restrict__ b_out,
                                                     float* __restrict__ out)
{
    __shared__ unsigned short lds[2][2][128 * 64];
    const int t  = threadIdx.x;
    const int n0 = blockIdx.x * 128;
    const int m0 = blockIdx.y * 128;
    const int b  = blockIdx.z;
    const unsigned short* gA = fbf + ((size_t)b * CIN + m0) * CIN;
    const unsigned short* gB = xt + ((size_t)b * NPIX + n0) * CIN;

    f32x4 acc[4][4] = {};
    stage256(gA, CIN, lds[0][0], t);
    stage256(gB, CIN, lds[0][1], t);
    __syncthreads();
    const int lane = t & 63, wid = t >> 6;
    const int wr = (wid >> 1) * 64, wc = (wid & 1) * 64;
    const int lrow = lane & 15, lk = (lane >> 4) * 8;
#pragma unroll
    for (int kt = 0; kt < 4; ++kt) {
        const int cur = kt & 1;
        if (kt < 3) {
            stage256(gA + (kt + 1) * 64, CIN, lds[cur ^ 1][0], t);
            stage256(gB + (kt + 1) * 64, CIN, lds[cur ^ 1][1], t);
        }
#pragma unroll
        for (int ks = 0; ks < 2; ++ks) {
            bf16x8 a[4], bb[4];
#pragma unroll
            for (int f = 0; f < 4; ++f) {
                a[f]  = *reinterpret_cast<const bf16x8*>(&lds[cur][0][swz(wr + f * 16 + lrow, ks * 32 + lk)]);
                bb[f] = *reinterpret_cast<const bf16x8*>(&lds[cur][1][swz(wc + f * 16 + lrow, ks * 32 + lk)]);
            }
#pragma unroll
            for (int fi = 0; fi < 4; ++fi)
#pragma unroll
                for (int fj = 0; fj < 4; ++fj)
                    acc[fi][fj] = __builtin_amdgcn_mfma_f32_16x16x32_bf16(
                        a[fi], bb[fj], acc[fi][fj], 0, 0, 0);
        }
        __syncthreads();
    }

    const int col = lane & 15, r0q = (lane >> 4) * 4;
#pragma unroll
    for (int fi = 0; fi < 4; ++fi)
#pragma unroll
        for (int r = 0; r < 4; ++r) {
            const int o = m0 + wr + fi * 16 + r0q + r;
            const float bias = b_out[o];
#pragma unroll
            for (int fj = 0; fj < 4; ++fj)
                out[((size_t)b * CIN + o) * NPIX + n0 + wc + fj * 16 + col] =
                    acc[fi][fj][r] + bias;
        }
}

// ---------------------------------------------------------------------------
extern "C" void kernel_launch(void* const* d_in, const int* in_sizes, int n_in,
                              void* d_out, int out_size, void* d_ws, size_t ws_size,
                              hipStream_t stream)
{
    const float* x     = (const float*)d_in[0];
    const float* w_qkv = (const float*)d_in[1];
    const float* w_out = (const float*)d_in[2];
    const float* b_out = (const float*)d_in[3];
    float* out = (float*)d_out;

    char* ws = (char*)d_ws;
    unsigned short* xt   = (unsigned short*)ws;                      // 32 MB
    unsigned short* xbf  = (unsigned short*)(ws + (32ull  << 20));   // 32 MB
    unsigned short* wbf  = (unsigned short*)(ws + (64ull  << 20));   // 768 KB
    float*          S    = (float*)(ws + (65ull  << 20));            // 8 KB
    float*          Gp   = (float*)(ws + (66ull  << 20));            // 33.5 MB
    float*          G    = (float*)(ws + (100ull << 20));            // 2 MB
    float*          ctx_s= (float*)(ws + (103ull << 20));            // 1 MB
    float*          Abar = (float*)(ws + (105ull << 20));            // 2 MB
    unsigned short* fbf  = (unsigned short*)(ws + (108ull << 20));   // 512 KB

    hipMemsetAsync(S, 0, 2048 * sizeof(float), stream);
    xt_convert<<<dim3(NPIX / 64, CIN / 64, NB), 256, 0, stream>>>(x, xt, xbf);
    wconv<<<1536, 256, 0, stream>>>(w_qkv, wbf);
    kg_fused<<<dim3(16, HEADS, NB), 512, 0, stream>>>(xt, xbf, wbf, Gp, S);
    g_reduce<<<2048, 256, 0, stream>>>(Gp, G);
    ctx_k<<<dim3(128, 16), 128, 0, stream>>>(G, w_qkv, S, ctx_s);
    abar_kernel<<<dim3(512, NB), 256, 0, stream>>>(ctx_s, w_qkv, Abar);
    f_kernel<<<dim3(256, NB), 256, 0, stream>>>(Abar, w_out, fbf);
    out_gemm_mfma<<<dim3(NPIX / 128, CIN / 128, NB), 256, 0, stream>>>(xt, fbf, b_out, out);
}